// Round 2
// baseline (552.290 us; speedup 1.0000x reference)
//
#include <hip/hip_runtime.h>

#define N_NODES 50000
#define N_EDGES 800000

// ---------------------------------------------------------------------------
// Scatter-add of 64-wide feature rows along edges: msg[dst] += feat[src].
// One wave (64 lanes) per edge: lane f handles feature f. Reads of feat[src]
// rows are fully coalesced (256B per edge). Optionally counts degree.
// ---------------------------------------------------------------------------
__global__ void scatter_add_f64(const float* __restrict__ feat,
                                const int* __restrict__ src,
                                const int* __restrict__ dst,
                                float* __restrict__ msg,
                                float* __restrict__ cnt,
                                int nEdges) {
    long long tid = (long long)blockIdx.x * blockDim.x + threadIdx.x;
    int e = (int)(tid >> 6);
    int f = (int)(tid & 63);
    if (e >= nEdges) return;
    int s = src[e];
    int d = dst[e];
    float v = feat[(long long)s * 64 + f];
    atomicAdd(&msg[(long long)d * 64 + f], v);
    if (cnt != nullptr && f == 0) atomicAdd(&cnt[d], 1.0f);
}

// ---------------------------------------------------------------------------
// Fused SAGE linear stage: out[n][o] = relu?( (msg[n]/max(cnt,1)) . Wl[o]
//                                             + bl[o] + x[n] . Wr[o] )
// K = 64 input features. OUTF in {64, 32}. Block = 256 threads covering
// NPB = 256/OUTF nodes; weights staged in LDS with +1 pad (conflict-free:
// address o*65+k spreads across banks as o varies within a wave).
// ---------------------------------------------------------------------------
template <int OUTF, bool RELU>
__global__ void sage_mm(const float* __restrict__ msg,
                        const float* __restrict__ cnt,
                        const float* __restrict__ xroot,
                        const float* __restrict__ Wl,
                        const float* __restrict__ bl,
                        const float* __restrict__ Wr,
                        float* __restrict__ out,
                        int nNodes) {
    constexpr int K = 64;
    constexpr int NPB = 256 / OUTF;  // nodes per block
    __shared__ float Wl_s[OUTF][K + 1];
    __shared__ float Wr_s[OUTF][K + 1];
    __shared__ float bl_s[OUTF];
    __shared__ float aggr_s[NPB][K];
    __shared__ float x_s[NPB][K];

    // Stage weights + bias.
    for (int i = threadIdx.x; i < OUTF * K; i += blockDim.x) {
        int o = i >> 6, k = i & 63;
        Wl_s[o][k] = Wl[i];
        Wr_s[o][k] = Wr[i];
    }
    if (threadIdx.x < OUTF) bl_s[threadIdx.x] = bl[threadIdx.x];

    // Stage this block's node rows (mean-divide applied at load).
    int base = blockIdx.x * NPB;
    for (int i = threadIdx.x; i < NPB * K; i += blockDim.x) {
        int nl = i >> 6, k = i & 63;
        int n = base + nl;
        if (n < nNodes) {
            float inv = 1.0f / fmaxf(cnt[n], 1.0f);
            aggr_s[nl][k] = msg[(long long)n * K + k] * inv;
            x_s[nl][k] = xroot[(long long)n * K + k];
        }
    }
    __syncthreads();

    int nl = threadIdx.x / OUTF;
    int o = threadIdx.x % OUTF;
    int n = base + nl;
    if (n < nNodes) {
        float acc = bl_s[o];
#pragma unroll
        for (int k = 0; k < K; ++k)
            acc += aggr_s[nl][k] * Wl_s[o][k] + x_s[nl][k] * Wr_s[o][k];
        if (RELU) acc = fmaxf(acc, 0.0f);
        out[(long long)n * OUTF + o] = acc;
    }
}

extern "C" void kernel_launch(void* const* d_in, const int* in_sizes, int n_in,
                              void* d_out, int out_size, void* d_ws, size_t ws_size,
                              hipStream_t stream) {
    const float* x   = (const float*)d_in[0];
    const int*   ei  = (const int*)d_in[1];   // (2, N_EDGES) int32
    const float* Wl1 = (const float*)d_in[2];
    const float* bl1 = (const float*)d_in[3];
    const float* Wr1 = (const float*)d_in[4];
    const float* Wl2 = (const float*)d_in[5];
    const float* bl2 = (const float*)d_in[6];
    const float* Wr2 = (const float*)d_in[7];
    float* out = (float*)d_out;

    const int* src = ei;            // row 0
    const int* dst = ei + N_EDGES;  // row 1

    // Workspace layout (floats). Zeroed prefix: msg1 | cnt | msg2. Then h.
    float* ws   = (float*)d_ws;
    float* msg1 = ws;                        // N*64
    float* cnt  = msg1 + (size_t)N_NODES * 64;  // N
    float* msg2 = cnt + N_NODES;             // N*64
    float* h    = msg2 + (size_t)N_NODES * 64;  // N*64 (fully overwritten)

    size_t zero_bytes = ((size_t)N_NODES * 64 * 2 + N_NODES) * sizeof(float);
    hipMemsetAsync(d_ws, 0, zero_bytes, stream);

    const int BLK = 256;
    const int scatter_blocks = (int)(((long long)N_EDGES * 64) / BLK);  // exact

    // Layer 1
    scatter_add_f64<<<scatter_blocks, BLK, 0, stream>>>(x, src, dst, msg1, cnt, N_EDGES);
    sage_mm<64, true><<<(N_NODES + 3) / 4, BLK, 0, stream>>>(msg1, cnt, x, Wl1, bl1, Wr1, h, N_NODES);

    // Layer 2 (same graph: reuse cnt)
    scatter_add_f64<<<scatter_blocks, BLK, 0, stream>>>(h, src, dst, msg2, nullptr, N_EDGES);
    sage_mm<32, false><<<(N_NODES + 7) / 8, BLK, 0, stream>>>(msg2, cnt, h, Wl2, bl2, Wr2, out, N_NODES);
}

// Round 3
// 284.902 us; speedup vs baseline: 1.9385x; 1.9385x over previous
//
#include <hip/hip_runtime.h>

#define N_NODES 50000
#define N_EDGES 800000
#define SCAN_BLK 256
#define SCAN_EPT 4                      // elems per thread
#define SCAN_NBLK ((N_NODES + SCAN_BLK * SCAN_EPT - 1) / (SCAN_BLK * SCAN_EPT))  // 49

// ---------------------------------------------------------------------------
// CSR build: histogram -> 3-pass exclusive scan -> fill
// ---------------------------------------------------------------------------
__global__ void deg_hist(const int* __restrict__ dst, int* __restrict__ deg) {
    int e = blockIdx.x * 256 + threadIdx.x;
    if (e < N_EDGES) atomicAdd(&deg[dst[e]], 1);
}

__global__ void scan_p1(const int* __restrict__ deg, int* __restrict__ thrOff,
                        int* __restrict__ partial) {
    int b = blockIdx.x, t = threadIdx.x;
    int base = (b * SCAN_BLK + t) * SCAN_EPT;
    int s = 0;
#pragma unroll
    for (int j = 0; j < SCAN_EPT; ++j) {
        int i = base + j;
        if (i < N_NODES) s += deg[i];
    }
    __shared__ int sh[SCAN_BLK];
    sh[t] = s;
    __syncthreads();
    for (int off = 1; off < SCAN_BLK; off <<= 1) {
        int v = (t >= off) ? sh[t - off] : 0;
        __syncthreads();
        sh[t] += v;
        __syncthreads();
    }
    thrOff[b * SCAN_BLK + t] = sh[t] - s;  // exclusive
    if (t == SCAN_BLK - 1) partial[b] = sh[t];
}

__global__ void scan_p2(const int* __restrict__ partial, int* __restrict__ partialOff) {
    if (threadIdx.x == 0) {
        int run = 0;
        for (int b = 0; b < SCAN_NBLK; ++b) {
            int v = partial[b];
            partialOff[b] = run;
            run += v;
        }
    }
}

__global__ void scan_p3(const int* __restrict__ deg, const int* __restrict__ thrOff,
                        const int* __restrict__ partialOff, int* __restrict__ ptr) {
    int b = blockIdx.x, t = threadIdx.x;
    int base = (b * SCAN_BLK + t) * SCAN_EPT;
    int run = partialOff[b] + thrOff[b * SCAN_BLK + t];
#pragma unroll
    for (int j = 0; j < SCAN_EPT; ++j) {
        int i = base + j;
        if (i < N_NODES) {
            ptr[i] = run;
            run += deg[i];
        }
    }
    if (b == 0 && t == 0) ptr[N_NODES] = N_EDGES;
}

__global__ void csr_fill(const int* __restrict__ src, const int* __restrict__ dst,
                         const int* __restrict__ ptr, int* __restrict__ cursor,
                         int* __restrict__ csr) {
    int e = blockIdx.x * 256 + threadIdx.x;
    if (e < N_EDGES) {
        int d = dst[e];
        int slot = atomicAdd(&cursor[d], 1);
        csr[ptr[d] + slot] = src[e];
    }
}

// ---------------------------------------------------------------------------
// Dual linear: Y = X @ Wl^T, Z = X @ Wr^T.  K=64 input features.
// Block 256 threads; NPB = 256/OUTF nodes per block; weights + rows in LDS,
// rows padded to 68 floats (16B-aligned rows, banks spread for b128 reads).
// 50000 divisible by NPB (4 or 8) -> no bounds checks in compute.
// ---------------------------------------------------------------------------
template <int OUTF>
__global__ void mm_dual(const float* __restrict__ X,
                        const float* __restrict__ Wl,
                        const float* __restrict__ Wr,
                        float* __restrict__ Y,
                        float* __restrict__ Z) {
    constexpr int K = 64;
    constexpr int NPB = 256 / OUTF;
    constexpr int PAD = 68;
    __shared__ float wl_s[OUTF * PAD];
    __shared__ float wr_s[OUTF * PAD];
    __shared__ float x_s[NPB * PAD];
    int t = threadIdx.x;

    for (int i = t; i < OUTF * (K / 4); i += 256) {
        int o = i >> 4, k4 = i & 15;
        *reinterpret_cast<float4*>(&wl_s[o * PAD + k4 * 4]) =
            reinterpret_cast<const float4*>(Wl)[i];
        *reinterpret_cast<float4*>(&wr_s[o * PAD + k4 * 4]) =
            reinterpret_cast<const float4*>(Wr)[i];
    }
    int base = blockIdx.x * NPB;
    for (int i = t; i < NPB * (K / 4); i += 256) {
        int nl = i >> 4, k4 = i & 15;
        *reinterpret_cast<float4*>(&x_s[nl * PAD + k4 * 4]) =
            reinterpret_cast<const float4*>(X)[(size_t)base * (K / 4) + i];
    }
    __syncthreads();

    int nl = t / OUTF, o = t % OUTF;
    const float4* xv = reinterpret_cast<const float4*>(&x_s[nl * PAD]);
    const float4* lv = reinterpret_cast<const float4*>(&wl_s[o * PAD]);
    const float4* rv = reinterpret_cast<const float4*>(&wr_s[o * PAD]);
    float4 aY = {0.f, 0.f, 0.f, 0.f}, aZ = {0.f, 0.f, 0.f, 0.f};
#pragma unroll
    for (int kk = 0; kk < K / 4; ++kk) {
        float4 x4 = xv[kk], l4 = lv[kk], r4 = rv[kk];
        aY.x += x4.x * l4.x; aY.y += x4.y * l4.y;
        aY.z += x4.z * l4.z; aY.w += x4.w * l4.w;
        aZ.x += x4.x * r4.x; aZ.y += x4.y * r4.y;
        aZ.z += x4.z * r4.z; aZ.w += x4.w * r4.w;
    }
    int n = base + nl;
    Y[(size_t)n * OUTF + o] = (aY.x + aY.y) + (aY.z + aY.w);
    Z[(size_t)n * OUTF + o] = (aZ.x + aZ.y) + (aZ.z + aZ.w);
}

// ---------------------------------------------------------------------------
// Gather-aggregate + residual: Out[n] = act( mean_{s in nbr(n)} Yin[s]
//                                            + bias + R[n] )
// F=64: one wave per node (lane = feature). F=32: two nodes per wave.
// No atomics. CSR reads broadcast within (sub-)wave; row reads coalesced.
// ---------------------------------------------------------------------------
template <int F, bool RELU>
__global__ void agg_add(const float* __restrict__ Yin,
                        const float* __restrict__ R,
                        const float* __restrict__ bias,
                        const int* __restrict__ ptr,
                        const int* __restrict__ csr,
                        float* __restrict__ Out) {
    constexpr int NPW = 64 / F;       // nodes per wave
    constexpr int NPB = 4 * NPW;      // 4 waves per block
    int wid = threadIdx.x >> 6, lane = threadIdx.x & 63;
    int sub = lane / F, f = lane % F;
    int n = blockIdx.x * NPB + wid * NPW + sub;

    int beg = ptr[n], end = ptr[n + 1];
    float acc = 0.f;
    int i = beg;
    for (; i + 3 < end; i += 4) {
        int s0 = csr[i], s1 = csr[i + 1], s2 = csr[i + 2], s3 = csr[i + 3];
        acc += Yin[(size_t)s0 * F + f];
        acc += Yin[(size_t)s1 * F + f];
        acc += Yin[(size_t)s2 * F + f];
        acc += Yin[(size_t)s3 * F + f];
    }
    for (; i < end; ++i) acc += Yin[(size_t)csr[i] * F + f];

    float inv = 1.0f / fmaxf((float)(end - beg), 1.0f);
    float v = acc * inv + bias[f] + R[(size_t)n * F + f];
    if (RELU) v = fmaxf(v, 0.f);
    Out[(size_t)n * F + f] = v;
}

extern "C" void kernel_launch(void* const* d_in, const int* in_sizes, int n_in,
                              void* d_out, int out_size, void* d_ws, size_t ws_size,
                              hipStream_t stream) {
    const float* x   = (const float*)d_in[0];
    const int*   ei  = (const int*)d_in[1];   // (2, N_EDGES) int32
    const float* Wl1 = (const float*)d_in[2];
    const float* bl1 = (const float*)d_in[3];
    const float* Wr1 = (const float*)d_in[4];
    const float* Wl2 = (const float*)d_in[5];
    const float* bl2 = (const float*)d_in[6];
    const float* Wr2 = (const float*)d_in[7];
    float* out = (float*)d_out;

    const int* src = ei;
    const int* dst = ei + N_EDGES;

    // Workspace layout (4B units). deg+cursor are the only zero-init region.
    int* iw = (int*)d_ws;
    int* deg        = iw;                       // 50000  (zeroed)
    int* cursor     = deg + N_NODES;            // 50000  (zeroed)
    int* ptr        = cursor + N_NODES;         // 50004 (50001 used, padded)
    int* partial    = ptr + 50004;              // 64
    int* partialOff = partial + 64;             // 64
    int* thrOff     = partialOff + 64;          // 49*256 = 12544
    int* csr        = thrOff + SCAN_NBLK * SCAN_BLK;  // 800000
    float* bufA = (float*)(csr + N_EDGES);      // 50000*64
    float* bufB = bufA + (size_t)N_NODES * 64;  // 50000*64
    float* h    = bufB + (size_t)N_NODES * 64;  // 50000*64

    hipMemsetAsync(deg, 0, 2 * N_NODES * sizeof(int), stream);

    // CSR build (shared by both layers)
    deg_hist<<<N_EDGES / 256, 256, 0, stream>>>(dst, deg);
    scan_p1<<<SCAN_NBLK, SCAN_BLK, 0, stream>>>(deg, thrOff, partial);
    scan_p2<<<1, 64, 0, stream>>>(partial, partialOff);
    scan_p3<<<SCAN_NBLK, SCAN_BLK, 0, stream>>>(deg, thrOff, partialOff, ptr);
    csr_fill<<<N_EDGES / 256, 256, 0, stream>>>(src, dst, ptr, cursor, csr);

    // Layer 1: y = x@Wl1^T, z = x@Wr1^T; h = relu(mean-aggr(y) + bl1 + z)
    mm_dual<64><<<N_NODES / 4, 256, 0, stream>>>(x, Wl1, Wr1, bufA, bufB);
    agg_add<64, true><<<N_NODES / 4, 256, 0, stream>>>(bufA, bufB, bl1, ptr, csr, h);

    // Layer 2: p = h@Wl2^T, r = h@Wr2^T; out = mean-aggr(p) + bl2 + r
    mm_dual<32><<<N_NODES / 8, 256, 0, stream>>>(h, Wl2, Wr2, bufA, bufB);
    agg_add<32, false><<<N_NODES / 8, 256, 0, stream>>>(bufA, bufB, bl2, ptr, csr, out);
}